// Round 2
// baseline (671.419 us; speedup 1.0000x reference)
//
#include <hip/hip_runtime.h>
#include <stdint.h>

#define S_LEN 2048
#define NH 16
#define DKH 64
#define NB 4
#define DM 1024
#define MROWS (NB * S_LEN)  // 8192

typedef __attribute__((ext_vector_type(4))) float f32x4;
typedef __attribute__((ext_vector_type(8))) short bf16x8;
typedef __attribute__((ext_vector_type(4))) unsigned int u32x4;

static __device__ __forceinline__ unsigned short f2bf(float x) {
    unsigned int u = __builtin_bit_cast(unsigned int, x);
    return (unsigned short)((u + 0x7FFFu + ((u >> 16) & 1u)) >> 16);
}

// CK-style addrspace cast via uintptr_t (apertures are 4GiB-aligned, low 32 bits = LDS offset)
static __device__ __forceinline__ void gld_lds16(const void* g, void* lds) {
    auto gp = (const __attribute__((address_space(1))) unsigned int*)(uintptr_t)(g);
    auto lp = (__attribute__((address_space(3))) unsigned int*)(uintptr_t)(lds);
    __builtin_amdgcn_global_load_lds(gp, lp, 16, 0, 0);
}

// ---------------- fp32 -> bf16 convert (up to 3 tensors via gridDim.z) ----------------
__global__ __launch_bounds__(256) void cvt3_f32_bf16(
    const float* __restrict__ i0, const float* __restrict__ i1, const float* __restrict__ i2,
    unsigned short* __restrict__ o0, unsigned short* __restrict__ o1, unsigned short* __restrict__ o2,
    int nvec)
{
    const float* in = (blockIdx.z == 0) ? i0 : (blockIdx.z == 1) ? i1 : i2;
    unsigned short* out = (blockIdx.z == 0) ? o0 : (blockIdx.z == 1) ? o1 : o2;
    const int stride = gridDim.x * blockDim.x;
    for (int i = blockIdx.x * blockDim.x + threadIdx.x; i < nvec; i += stride) {
        float4 v = ((const float4*)in)[i];
        ushort4 r;
        r.x = f2bf(v.x); r.y = f2bf(v.y); r.z = f2bf(v.z); r.w = f2bf(v.w);
        ((ushort4*)out)[i] = r;
    }
}

// ---------------- NT GEMM: C[m,n] = sum_k A[m,k]*B[n,k], M=8192 N=1024 K=1024 ----------------
// 128x128 tile, BK=64, 256 threads (4 waves, 2x2), 16x16x32 bf16 MFMA, global_load_lds staging.
// MODE 1: write bf16 head-split [B,H,S,64].  MODE 2: write fp32 [M,N] row-major.
template <int MODE>
__global__ __launch_bounds__(256) void gemm_bt(
    const unsigned short* __restrict__ A0, const unsigned short* __restrict__ A1, const unsigned short* __restrict__ A2,
    const unsigned short* __restrict__ B0, const unsigned short* __restrict__ B1, const unsigned short* __restrict__ B2,
    void* __restrict__ C0, void* __restrict__ C1, void* __restrict__ C2)
{
    __shared__ __align__(16) unsigned short As[128 * 64];
    __shared__ __align__(16) unsigned short Bs[128 * 64];
    const unsigned short* A = (blockIdx.z == 0) ? A0 : (blockIdx.z == 1) ? A1 : A2;
    const unsigned short* B = (blockIdx.z == 0) ? B0 : (blockIdx.z == 1) ? B1 : B2;
    void* C = (blockIdx.z == 0) ? C0 : (blockIdx.z == 1) ? C1 : C2;

    const int t = threadIdx.x;
    const int w = t >> 6, l = t & 63;
    const int wr = w >> 1, wc = w & 1;
    const int m0 = blockIdx.y * 128, n0 = blockIdx.x * 128;

    f32x4 acc[4][4] = {};

    // staging addresses: thread t covers row (t>>3), 16B chunk (t&7); LDS dest linear in t
    const unsigned short* Ag = A + (size_t)(m0 + (t >> 3)) * 1024 + (t & 7) * 8;
    const unsigned short* Bg = B + (size_t)(n0 + (t >> 3)) * 1024 + (t & 7) * 8;
    unsigned short* AsW = &As[w * 512];
    unsigned short* BsW = &Bs[w * 512];

    for (int kt = 0; kt < 16; ++kt) {
        __syncthreads();
        const int kb = kt * 64;
#pragma unroll
        for (int i = 0; i < 4; ++i) {
            gld_lds16(Ag + (size_t)i * 32 * 1024 + kb, AsW + i * 2048);
            gld_lds16(Bg + (size_t)i * 32 * 1024 + kb, BsW + i * 2048);
        }
        __syncthreads();
#pragma unroll
        for (int kk = 0; kk < 2; ++kk) {
            const int koff = kk * 32 + (l >> 4) * 8;
            bf16x8 af[4], bfr[4];
#pragma unroll
            for (int m = 0; m < 4; ++m)
                af[m] = *(const bf16x8*)&As[(wr * 64 + m * 16 + (l & 15)) * 64 + koff];
#pragma unroll
            for (int n = 0; n < 4; ++n)
                bfr[n] = *(const bf16x8*)&Bs[(wc * 64 + n * 16 + (l & 15)) * 64 + koff];
#pragma unroll
            for (int m = 0; m < 4; ++m)
#pragma unroll
                for (int n = 0; n < 4; ++n)
                    acc[m][n] = __builtin_amdgcn_mfma_f32_16x16x32_bf16(af[m], bfr[n], acc[m][n], 0, 0, 0);
        }
    }

#pragma unroll
    for (int m = 0; m < 4; ++m) {
#pragma unroll
        for (int n = 0; n < 4; ++n) {
#pragma unroll
            for (int r = 0; r < 4; ++r) {
                const int row = m0 + wr * 64 + m * 16 + (l >> 4) * 4 + r;  // = b*2048 + s
                const int col = n0 + wc * 64 + n * 16 + (l & 15);          // = h*64 + dk
                if (MODE == 1) {
                    ((unsigned short*)C)[(size_t)((row >> 11) * 16 + (col >> 6)) * (S_LEN * 64) +
                                         (size_t)(row & 2047) * 64 + (col & 63)] = f2bf(acc[m][n][r]);
                } else {
                    ((float*)C)[(size_t)row * 1024 + col] = acc[m][n][r];
                }
            }
        }
    }
}

// ---------------- causal flash attention: Q/K/V [B*H, S, 64] bf16 -> Ao [B, S, 1024] bf16 ----------------
// BQ = BKV = 128, 256 threads (4 waves), wave w owns q rows [w*32, w*32+32)
__global__ __launch_bounds__(256) void attn_fwd(
    const unsigned short* __restrict__ Qh, const unsigned short* __restrict__ Kh,
    const unsigned short* __restrict__ Vh, unsigned short* __restrict__ Ao)
{
    __shared__ __align__(16) unsigned short Qs[128 * 64];    // [q][dk], 16B-chunk XOR swizzle
    __shared__ __align__(16) unsigned short Ks[128 * 64];    // [kv][dk], swizzled
    __shared__ __align__(16) unsigned short Vts[64 * 128];   // [dk][kv], swizzled
    __shared__ __align__(16) unsigned short Ps[128 * 128];   // [q][kv], swizzled

    const int t = threadIdx.x, w = t >> 6, l = t & 63;
    const int bh = blockIdx.y;
    const int b = bh >> 4, h = bh & 15;
    const int q0 = blockIdx.x * 128;
    const unsigned short* Qg = Qh + (size_t)bh * S_LEN * 64;
    const unsigned short* Kg = Kh + (size_t)bh * S_LEN * 64;
    const unsigned short* Vg = Vh + (size_t)bh * S_LEN * 64;

#pragma unroll
    for (int i = 0; i < 4; ++i) {
        const int idx = i * 256 + t;
        const int row = idx >> 3, ch = idx & 7;
        u32x4 v = *(const u32x4*)&Qg[(size_t)(q0 + row) * 64 + ch * 8];
        *(u32x4*)&Qs[row * 64 + ((ch ^ (row & 7)) << 3)] = v;
    }

    float mrow[2][4], lrow[2][4];
    f32x4 oacc[2][4] = {};
#pragma unroll
    for (int m = 0; m < 2; ++m)
#pragma unroll
        for (int r = 0; r < 4; ++r) { mrow[m][r] = -1e30f; lrow[m][r] = 0.f; }

    const int ntile = blockIdx.x + 1;
    for (int kv = 0; kv < ntile; ++kv) {
        const int kv0 = kv * 128;
        __syncthreads();  // protect prev iter's K/Vt reads (and first-iter Q stage)
#pragma unroll
        for (int i = 0; i < 4; ++i) {
            const int idx = i * 256 + t;
            const int row = idx >> 3, ch = idx & 7;
            u32x4 vk = *(const u32x4*)&Kg[(size_t)(kv0 + row) * 64 + ch * 8];
            *(u32x4*)&Ks[row * 64 + ((ch ^ (row & 7)) << 3)] = vk;
            u32x4 vv = *(const u32x4*)&Vg[(size_t)(kv0 + row) * 64 + ch * 8];
            const unsigned short* pv = (const unsigned short*)&vv;
#pragma unroll
            for (int j = 0; j < 8; ++j) {
                const int dk = ch * 8 + j;
                Vts[dk * 128 + (((row >> 3) ^ (dk & 15)) << 3) + (row & 7)] = pv[j];
            }
        }
        __syncthreads();

        // QK^T : S[q, kv]
        f32x4 sc[2][8] = {};
#pragma unroll
        for (int kk = 0; kk < 2; ++kk) {
            const int chb = kk * 4 + (l >> 4);
            bf16x8 aq[2];
#pragma unroll
            for (int m = 0; m < 2; ++m) {
                const int row = w * 32 + m * 16 + (l & 15);
                aq[m] = *(const bf16x8*)&Qs[row * 64 + ((chb ^ (row & 7)) << 3)];
            }
#pragma unroll
            for (int n = 0; n < 8; ++n) {
                const int rk = n * 16 + (l & 15);
                bf16x8 bk = *(const bf16x8*)&Ks[rk * 64 + ((chb ^ (rk & 7)) << 3)];
#pragma unroll
                for (int m = 0; m < 2; ++m)
                    sc[m][n] = __builtin_amdgcn_mfma_f32_16x16x32_bf16(aq[m], bk, sc[m][n], 0, 0, 0);
            }
        }

        const bool diag = (kv == (int)blockIdx.x);
#pragma unroll
        for (int m = 0; m < 2; ++m) {
            float rmax[4] = {-1e30f, -1e30f, -1e30f, -1e30f};
#pragma unroll
            for (int n = 0; n < 8; ++n) {
#pragma unroll
                for (int r = 0; r < 4; ++r) {
                    float v = sc[m][n][r] * 0.125f;  // 1/sqrt(64)
                    if (diag) {
                        const int qg_ = q0 + w * 32 + m * 16 + (l >> 4) * 4 + r;
                        const int kg_ = kv0 + n * 16 + (l & 15);
                        if (kg_ > qg_) v = -1e30f;
                    }
                    sc[m][n][r] = v;
                    rmax[r] = fmaxf(rmax[r], v);
                }
            }
#pragma unroll
            for (int r = 0; r < 4; ++r) {
#pragma unroll
                for (int d = 1; d < 16; d <<= 1)
                    rmax[r] = fmaxf(rmax[r], __shfl_xor(rmax[r], d));
            }
            float alpha[4];
#pragma unroll
            for (int r = 0; r < 4; ++r) {
                const float mnew = fmaxf(mrow[m][r], rmax[r]);
                alpha[r] = __expf(mrow[m][r] - mnew);
                mrow[m][r] = mnew;
                lrow[m][r] *= alpha[r];
            }
#pragma unroll
            for (int d = 0; d < 4; ++d)
#pragma unroll
                for (int r = 0; r < 4; ++r)
                    oacc[m][d][r] *= alpha[r];
            float rs[4] = {0.f, 0.f, 0.f, 0.f};
#pragma unroll
            for (int n = 0; n < 8; ++n) {
#pragma unroll
                for (int r = 0; r < 4; ++r) {
                    const float p = __expf(sc[m][n][r] - mrow[m][r]);
                    sc[m][n][r] = p;
                    rs[r] += p;
                }
            }
#pragma unroll
            for (int r = 0; r < 4; ++r) {
#pragma unroll
                for (int d = 1; d < 16; d <<= 1)
                    rs[r] += __shfl_xor(rs[r], d);
                lrow[m][r] += rs[r];
            }
            // write P (bf16, swizzled); rows are wave-local -> no barrier needed
#pragma unroll
            for (int n = 0; n < 8; ++n) {
#pragma unroll
                for (int r = 0; r < 4; ++r) {
                    const int row = w * 32 + m * 16 + (l >> 4) * 4 + r;
                    const int col = n * 16 + (l & 15);
                    Ps[row * 128 + (((col >> 3) ^ (row & 15)) << 3) + (col & 7)] = f2bf(sc[m][n][r]);
                }
            }
        }

        // PV : O += P[q, kv] * V[kv, dk]  (B operand from Vt[dk][kv])
#pragma unroll
        for (int kk2 = 0; kk2 < 4; ++kk2) {
            const int ch = kk2 * 4 + (l >> 4);
            bf16x8 ap[2], bv[4];
#pragma unroll
            for (int m = 0; m < 2; ++m) {
                const int row = w * 32 + m * 16 + (l & 15);
                ap[m] = *(const bf16x8*)&Ps[row * 128 + ((ch ^ (row & 15)) << 3)];
            }
#pragma unroll
            for (int d = 0; d < 4; ++d) {
                const int rv = d * 16 + (l & 15);
                bv[d] = *(const bf16x8*)&Vts[rv * 128 + ((ch ^ (rv & 15)) << 3)];
            }
#pragma unroll
            for (int m = 0; m < 2; ++m)
#pragma unroll
                for (int d = 0; d < 4; ++d)
                    oacc[m][d] = __builtin_amdgcn_mfma_f32_16x16x32_bf16(ap[m], bv[d], oacc[m][d], 0, 0, 0);
        }
    }

    // epilogue: O / l -> bf16 -> [B, S, H*64]
#pragma unroll
    for (int m = 0; m < 2; ++m)
#pragma unroll
        for (int d = 0; d < 4; ++d)
#pragma unroll
            for (int r = 0; r < 4; ++r) {
                const int sq = q0 + w * 32 + m * 16 + (l >> 4) * 4 + r;
                const int dk = d * 16 + (l & 15);
                const float o = oacc[m][d][r] / lrow[m][r];
                Ao[(size_t)b * (S_LEN * 1024) + (size_t)sq * 1024 + h * 64 + dk] = f2bf(o);
            }
}

extern "C" void kernel_launch(void* const* d_in, const int* in_sizes, int n_in,
                              void* d_out, int out_size, void* d_ws, size_t ws_size,
                              hipStream_t stream) {
    (void)in_sizes; (void)n_in; (void)out_size; (void)ws_size;
    const float* q_in = (const float*)d_in[0];
    const float* k_in = (const float*)d_in[1];
    const float* v_in = (const float*)d_in[2];
    // d_in[3] = causal mask (tril) -> implemented analytically in attn_fwd
    const float* w_q = (const float*)d_in[4];
    const float* w_k = (const float*)d_in[5];
    const float* w_v = (const float*)d_in[6];
    const float* w_o = (const float*)d_in[7];

    const size_t NELEM = (size_t)MROWS * 1024;  // 8388608
    unsigned short* qb  = (unsigned short*)d_ws;
    unsigned short* kb  = qb + NELEM;
    unsigned short* vb  = kb + NELEM;
    unsigned short* wqb = vb + NELEM;
    unsigned short* wkb = wqb + 1024 * 1024;
    unsigned short* wvb = wkb + 1024 * 1024;
    unsigned short* wob = wvb + 1024 * 1024;
    unsigned short* Qhp = wob + 1024 * 1024;
    unsigned short* Khp = Qhp + NELEM;
    unsigned short* Vhp = Khp + NELEM;
    unsigned short* Aop = qb;  // reuse: q/k/v bf16 dead after QKV GEMMs

    cvt3_f32_bf16<<<dim3(1024, 1, 3), 256, 0, stream>>>(q_in, k_in, v_in, qb, kb, vb, (int)(NELEM / 4));
    cvt3_f32_bf16<<<dim3(256, 1, 3), 256, 0, stream>>>(w_q, w_k, w_v, wqb, wkb, wvb, 1024 * 1024 / 4);
    cvt3_f32_bf16<<<dim3(256, 1, 1), 256, 0, stream>>>(w_o, nullptr, nullptr, wob, nullptr, nullptr, 1024 * 1024 / 4);

    gemm_bt<1><<<dim3(8, 64, 3), 256, 0, stream>>>(qb, kb, vb, wqb, wkb, wvb, Qhp, Khp, Vhp);
    attn_fwd<<<dim3(16, 64), 256, 0, stream>>>(Qhp, Khp, Vhp, Aop);
    gemm_bt<2><<<dim3(8, 64, 1), 256, 0, stream>>>(Aop, nullptr, nullptr, wob, nullptr, nullptr,
                                                   d_out, nullptr, nullptr);
}

// Round 4
// 442.624 us; speedup vs baseline: 1.5169x; 1.5169x over previous
//
#include <hip/hip_runtime.h>
#include <stdint.h>

#define S_LEN 2048
#define NH 16
#define DKH 64
#define NB 4
#define DM 1024
#define MROWS (NB * S_LEN)  // 8192

typedef __attribute__((ext_vector_type(4))) float f32x4;
typedef __attribute__((ext_vector_type(8))) short bf16x8;
typedef __attribute__((ext_vector_type(4))) unsigned int u32x4;

static __device__ __forceinline__ unsigned short f2bf(float x) {
    unsigned int u = __builtin_bit_cast(unsigned int, x);
    return (unsigned short)((u + 0x7FFFu + ((u >> 16) & 1u)) >> 16);
}
static __device__ __forceinline__ unsigned int pack2bf(float lo, float hi) {
    return (unsigned int)f2bf(lo) | ((unsigned int)f2bf(hi) << 16);
}

// CK-style addrspace cast via uintptr_t (apertures are 4GiB-aligned, low 32 bits = LDS offset)
static __device__ __forceinline__ void gld_lds16(const void* g, void* lds) {
    auto gp = (const __attribute__((address_space(1))) unsigned int*)(uintptr_t)(g);
    auto lp = (__attribute__((address_space(3))) unsigned int*)(uintptr_t)(lds);
    __builtin_amdgcn_global_load_lds(gp, lp, 16, 0, 0);
}

// ---------------- fp32 -> bf16 convert (up to 3 tensors via gridDim.z) ----------------
__global__ __launch_bounds__(256) void cvt3_f32_bf16(
    const float* __restrict__ i0, const float* __restrict__ i1, const float* __restrict__ i2,
    unsigned short* __restrict__ o0, unsigned short* __restrict__ o1, unsigned short* __restrict__ o2,
    int nvec)
{
    const float* in = (blockIdx.z == 0) ? i0 : (blockIdx.z == 1) ? i1 : i2;
    unsigned short* out = (blockIdx.z == 0) ? o0 : (blockIdx.z == 1) ? o1 : o2;
    const int stride = gridDim.x * blockDim.x;
    for (int i = blockIdx.x * blockDim.x + threadIdx.x; i < nvec; i += stride) {
        float4 v = ((const float4*)in)[i];
        ushort4 r;
        r.x = f2bf(v.x); r.y = f2bf(v.y); r.z = f2bf(v.z); r.w = f2bf(v.w);
        ((ushort4*)out)[i] = r;
    }
}

// ---------------- NT GEMM: C[m,n] = sum_k A[m,k]*B[n,k], M=8192 N=1024 K=1024 ----------------
// 128x128 tile, BK=64, 256 threads (4 waves, 2x2), 16x16x32 bf16 MFMA, global_load_lds staging.
// MODE 1: z=0,1 -> bf16 head-split [B,H,S,64] (z==0 scaled by qscale);
//         z=2   -> bf16 TRANSPOSED per-head V^T [B,H,64,S] (8B-vectorized stores).
// MODE 2: fp32 [M,N] row-major.
template <int MODE>
__global__ __launch_bounds__(256) void gemm_bt(
    const unsigned short* __restrict__ A0, const unsigned short* __restrict__ A1, const unsigned short* __restrict__ A2,
    const unsigned short* __restrict__ B0, const unsigned short* __restrict__ B1, const unsigned short* __restrict__ B2,
    void* __restrict__ C0, void* __restrict__ C1, void* __restrict__ C2, float qscale)
{
    __shared__ __align__(16) unsigned short As[128 * 64];
    __shared__ __align__(16) unsigned short Bs[128 * 64];
    const unsigned short* A = (blockIdx.z == 0) ? A0 : (blockIdx.z == 1) ? A1 : A2;
    const unsigned short* B = (blockIdx.z == 0) ? B0 : (blockIdx.z == 1) ? B1 : B2;
    void* C = (blockIdx.z == 0) ? C0 : (blockIdx.z == 1) ? C1 : C2;
    const float cscale = (MODE == 1 && blockIdx.z == 0) ? qscale : 1.0f;

    const int t = threadIdx.x;
    const int w = t >> 6, l = t & 63;
    const int wr = w >> 1, wc = w & 1;
    const int m0 = blockIdx.y * 128, n0 = blockIdx.x * 128;

    f32x4 acc[4][4] = {};

    const unsigned short* Ag = A + (size_t)(m0 + (t >> 3)) * 1024 + (t & 7) * 8;
    const unsigned short* Bg = B + (size_t)(n0 + (t >> 3)) * 1024 + (t & 7) * 8;
    unsigned short* AsW = &As[w * 512];
    unsigned short* BsW = &Bs[w * 512];

    for (int kt = 0; kt < 16; ++kt) {
        __syncthreads();
        const int kb = kt * 64;
#pragma unroll
        for (int i = 0; i < 4; ++i) {
            gld_lds16(Ag + (size_t)i * 32 * 1024 + kb, AsW + i * 2048);
            gld_lds16(Bg + (size_t)i * 32 * 1024 + kb, BsW + i * 2048);
        }
        __syncthreads();
#pragma unroll
        for (int kk = 0; kk < 2; ++kk) {
            const int koff = kk * 32 + (l >> 4) * 8;
            bf16x8 af[4], bfr[4];
#pragma unroll
            for (int m = 0; m < 4; ++m)
                af[m] = *(const bf16x8*)&As[(wr * 64 + m * 16 + (l & 15)) * 64 + koff];
#pragma unroll
            for (int n = 0; n < 4; ++n)
                bfr[n] = *(const bf16x8*)&Bs[(wc * 64 + n * 16 + (l & 15)) * 64 + koff];
#pragma unroll
            for (int m = 0; m < 4; ++m)
#pragma unroll
                for (int n = 0; n < 4; ++n)
                    acc[m][n] = __builtin_amdgcn_mfma_f32_16x16x32_bf16(af[m], bfr[n], acc[m][n], 0, 0, 0);
        }
    }

#pragma unroll
    for (int m = 0; m < 4; ++m) {
#pragma unroll
        for (int n = 0; n < 4; ++n) {
            const int rowb = m0 + wr * 64 + m * 16 + (l >> 4) * 4;       // +r = b*2048 + s
            const int col  = n0 + wc * 64 + n * 16 + (l & 15);           // = h*64 + dk
            if (MODE == 1 && blockIdx.z == 2) {
                // V^T store: [bh][dk][s], 4 consecutive s per lane -> 8B store
                const int bh = (rowb >> 11) * 16 + (col >> 6);
                const int dk = col & 63;
                const int s0 = rowb & 2047;
                const unsigned int w0 = pack2bf(acc[m][n][0], acc[m][n][1]);
                const unsigned int w1 = pack2bf(acc[m][n][2], acc[m][n][3]);
                *(uint2*)&((unsigned short*)C)[((size_t)bh * 64 + dk) * 2048 + s0] = make_uint2(w0, w1);
            } else {
#pragma unroll
                for (int r = 0; r < 4; ++r) {
                    const int row = rowb + r;
                    if (MODE == 1) {
                        ((unsigned short*)C)[(size_t)((row >> 11) * 16 + (col >> 6)) * (S_LEN * 64) +
                                             (size_t)(row & 2047) * 64 + (col & 63)] = f2bf(acc[m][n][r] * cscale);
                    } else {
                        ((float*)C)[(size_t)row * 1024 + col] = acc[m][n][r];
                    }
                }
            }
        }
    }
}

// ---------------- causal flash attention (swapped-QK^T, in-register softmax) ----------------
// Q/K [B*H, S, 64] bf16 (Q pre-scaled by 1/8), V^T [B*H, 64, S] bf16 -> Ao [B, S, 1024] bf16
// 512 threads = 8 waves, each wave owns 16 q-rows; BKV = 128.
// After mfma(A=K, B=Q): sc[nb] = S^T[k = nb*16+4g+r][q = c], g=l>>4, c=l&15.
// Only LDS: Vts[64 dk][16 chunks of 8 kv] bf16, chunk-phys = chunk-log ^ (dk&7)
// (swizzle applied by pre-swizzling the gld_lds GLOBAL source; LDS dest stays linear).
__global__ __launch_bounds__(512, 4) void attn_fwd(
    const unsigned short* __restrict__ Qh, const unsigned short* __restrict__ Kh,
    const unsigned short* __restrict__ Vth, unsigned short* __restrict__ Ao)
{
    __shared__ __align__(16) unsigned short Vts[64 * 128];  // 16 KiB

    const int t = threadIdx.x, w = t >> 6, l = t & 63;
    const int g = l >> 4, c = l & 15;
    const int bid = blockIdx.x;
    const int qi = 15 - (bid >> 6);   // heavy-first: 16-tile blocks dispatch first
    const int bh = bid & 63;          // same-bh blocks land on same XCD (64 % 8 == 0)
    const int b = bh >> 4, h = bh & 15;
    const int q0 = qi * 128;

    const unsigned short* Qg  = Qh  + (size_t)bh * (S_LEN * 64);
    const unsigned short* Kg  = Kh  + (size_t)bh * (S_LEN * 64);
    const unsigned short* Vtg = Vth + (size_t)bh * (64 * S_LEN);

    // Q B-frags for this wave's 16 rows (held in regs for all tiles)
    const int qrow = q0 + w * 16 + c;
    const unsigned short* Qp = Qg + (size_t)qrow * 64 + g * 8;
    bf16x8 qf[2];
    qf[0] = *(const bf16x8*)(Qp);
    qf[1] = *(const bf16x8*)(Qp + 32);

    // K read base (per-lane): + kv0*64 + kk*32 + nb*16*64
    const unsigned short* Kln = Kg + (size_t)c * 64 + g * 8;

    // V^T staging: this thread's two 16B chunks; linear LDS index L = w*128 + i*64 + l
    // logical (dk = L>>4, ch_log = (L&15) ^ (dk&7)); global src = Vtg + dk*2048 + kv0 + ch_log*8
    const int L0 = w * 128 + l, L1 = L0 + 64;
    const int dk0 = L0 >> 4, dk1 = L1 >> 4;
    const unsigned short* Vsrc0 = Vtg + (size_t)dk0 * 2048 + (((L0 & 15) ^ (dk0 & 7)) << 3);
    const unsigned short* Vsrc1 = Vtg + (size_t)dk1 * 2048 + (((L1 & 15) ^ (dk1 & 7)) << 3);
    unsigned short* Vdst0 = &Vts[(size_t)(w * 128) * 8];        // wave-uniform; HW adds lane*16B
    unsigned short* Vdst1 = &Vts[(size_t)(w * 128 + 64) * 8];

    float m_run = -1e30f, l_run = 0.0f;
    f32x4 oacc[4] = {};

    const int ntile = qi + 1;
    for (int kv = 0; kv < ntile; ++kv) {
        const int kv0 = kv * 128;
        __syncthreads();  // Vts free (prev tile's PV finished)

        // --- stage V^T tile (async; drains at the next __syncthreads) ---
        gld_lds16(Vsrc0 + kv0, Vdst0);
        gld_lds16(Vsrc1 + kv0, Vdst1);

        // --- QK^T (swapped): sc[nb] = S^T[k][q], K frags straight from global (L1-hot) ---
        f32x4 sc[8] = {};
#pragma unroll
        for (int kk = 0; kk < 2; ++kk) {
            const unsigned short* kp = Kln + (size_t)kv0 * 64 + kk * 32;
#pragma unroll
            for (int nb = 0; nb < 8; ++nb) {
                bf16x8 kfr = *(const bf16x8*)(kp + (size_t)nb * 16 * 64);
                sc[nb] = __builtin_amdgcn_mfma_f32_16x16x32_bf16(kfr, qf[kk], sc[nb], 0, 0, 0);
            }
        }

        // --- causal mask (diagonal tile only; scale already folded into Q) ---
        if (kv == qi) {
#pragma unroll
            for (int nb = 0; nb < 8; ++nb)
#pragma unroll
                for (int r = 0; r < 4; ++r)
                    if (kv0 + nb * 16 + 4 * g + r > qrow) sc[nb][r] = -1e30f;
        }

        // --- online softmax, fully in-register (q = c per lane) ---
        float mx = -1e30f;
#pragma unroll
        for (int nb = 0; nb < 8; ++nb)
#pragma unroll
            for (int r = 0; r < 4; ++r) mx = fmaxf(mx, sc[nb][r]);
        mx = fmaxf(mx, __shfl_xor(mx, 16));
        mx = fmaxf(mx, __shfl_xor(mx, 32));
        const float mnew = fmaxf(m_run, mx);
        const float alpha = __expf(m_run - mnew);
        m_run = mnew;

        float af[4];
#pragma unroll
        for (int r = 0; r < 4; ++r) af[r] = __shfl(alpha, 4 * g + r);
#pragma unroll
        for (int db = 0; db < 4; ++db)
#pragma unroll
            for (int r = 0; r < 4; ++r) oacc[db][r] *= af[r];

        float s = 0.0f;
#pragma unroll
        for (int nb = 0; nb < 8; ++nb)
#pragma unroll
            for (int r = 0; r < 4; ++r) {
                const float p = __expf(sc[nb][r] - m_run);
                sc[nb][r] = p;
                s += p;
            }
        s += __shfl_xor(s, 16);
        s += __shfl_xor(s, 32);
        l_run = l_run * alpha + s;

        // --- pack P to bf16 pairs; redistribute into PV A-frags via shfl ---
        unsigned int pk[8][2];
#pragma unroll
        for (int nb = 0; nb < 8; ++nb) {
            pk[nb][0] = pack2bf(sc[nb][0], sc[nb][1]);
            pk[nb][1] = pack2bf(sc[nb][2], sc[nb][3]);
        }
        const int srcA = 32 * (g & 1) + c;
        const int srcB = srcA + 16;
        const bool hi = (g >= 2);   // selects nb = 2*kk2 + 1
        unsigned int apw[4][4];
#pragma unroll
        for (int kk2 = 0; kk2 < 4; ++kk2) {
            const unsigned int a0 = __shfl(pk[2 * kk2][0], srcA), b0 = __shfl(pk[2 * kk2 + 1][0], srcA);
            const unsigned int a1 = __shfl(pk[2 * kk2][1], srcA), b1 = __shfl(pk[2 * kk2 + 1][1], srcA);
            const unsigned int a2 = __shfl(pk[2 * kk2][0], srcB), b2 = __shfl(pk[2 * kk2 + 1][0], srcB);
            const unsigned int a3 = __shfl(pk[2 * kk2][1], srcB), b3 = __shfl(pk[2 * kk2 + 1][1], srcB);
            apw[kk2][0] = hi ? b0 : a0;
            apw[kk2][1] = hi ? b1 : a1;
            apw[kk2][2] = hi ? b2 : a2;
            apw[kk2][3] = hi ? b3 : a3;
        }

        __syncthreads();  // V^T staged (gld_lds drained by barrier's vmcnt(0))

        // --- PV: O += P * V  (A = apw regs, B = V^T rows from LDS, swizzled chunks) ---
#pragma unroll
        for (int kk2 = 0; kk2 < 4; ++kk2) {
            const bf16x8 ap = __builtin_bit_cast(bf16x8, *(const u32x4*)apw[kk2]);
#pragma unroll
            for (int db = 0; db < 4; ++db) {
                const int d = db * 16 + c;
                const int chp = (4 * kk2 + g) ^ (d & 7);
                const bf16x8 bv = *(const bf16x8*)&Vts[d * 128 + chp * 8];
                oacc[db] = __builtin_amdgcn_mfma_f32_16x16x32_bf16(ap, bv, oacc[db], 0, 0, 0);
            }
        }
    }

    // --- epilogue: normalize, write [B, S, H*64] ---
    float li[4];
#pragma unroll
    for (int r = 0; r < 4; ++r) li[r] = __shfl(l_run, 4 * g + r);
#pragma unroll
    for (int db = 0; db < 4; ++db)
#pragma unroll
        for (int r = 0; r < 4; ++r) {
            const int sq = q0 + w * 16 + 4 * g + r;
            const int col = h * 64 + db * 16 + c;
            Ao[(size_t)b * (S_LEN * 1024) + (size_t)sq * 1024 + col] = f2bf(oacc[db][r] / li[r]);
        }
}

extern "C" void kernel_launch(void* const* d_in, const int* in_sizes, int n_in,
                              void* d_out, int out_size, void* d_ws, size_t ws_size,
                              hipStream_t stream) {
    (void)in_sizes; (void)n_in; (void)out_size; (void)ws_size;
    const float* q_in = (const float*)d_in[0];
    const float* k_in = (const float*)d_in[1];
    const float* v_in = (const float*)d_in[2];
    // d_in[3] = causal mask (tril) -> implemented analytically in attn_fwd
    const float* w_q = (const float*)d_in[4];
    const float* w_k = (const float*)d_in[5];
    const float* w_v = (const float*)d_in[6];
    const float* w_o = (const float*)d_in[7];

    const size_t NELEM = (size_t)MROWS * 1024;  // 8388608
    unsigned short* qb  = (unsigned short*)d_ws;
    unsigned short* kb  = qb + NELEM;
    unsigned short* vb  = kb + NELEM;
    unsigned short* wqb = vb + NELEM;
    unsigned short* wkb = wqb + 1024 * 1024;
    unsigned short* wvb = wkb + 1024 * 1024;
    unsigned short* wob = wvb + 1024 * 1024;
    unsigned short* Qhp = wob + 1024 * 1024;
    unsigned short* Khp = Qhp + NELEM;
    unsigned short* Vtp = Khp + NELEM;   // V^T [B*H, 64, S]
    unsigned short* Aop = qb;  // reuse: q/k/v bf16 dead after QKV GEMMs

    cvt3_f32_bf16<<<dim3(1024, 1, 3), 256, 0, stream>>>(q_in, k_in, v_in, qb, kb, vb, (int)(NELEM / 4));
    cvt3_f32_bf16<<<dim3(256, 1, 3), 256, 0, stream>>>(w_q, w_k, w_v, wqb, wkb, wvb, 1024 * 1024 / 4);
    cvt3_f32_bf16<<<dim3(256, 1, 1), 256, 0, stream>>>(w_o, nullptr, nullptr, wob, nullptr, nullptr, 1024 * 1024 / 4);

    gemm_bt<1><<<dim3(8, 64, 3), 256, 0, stream>>>(qb, kb, vb, wqb, wkb, wvb, Qhp, Khp, Vtp, 0.125f);
    attn_fwd<<<dim3(1024), 512, 0, stream>>>(Qhp, Khp, Vtp, Aop);
    gemm_bt<2><<<dim3(8, 64, 1), 256, 0, stream>>>(Aop, nullptr, nullptr, wob, nullptr, nullptr,
                                                   d_out, nullptr, nullptr, 1.0f);
}

// Round 6
// 343.117 us; speedup vs baseline: 1.9568x; 1.2900x over previous
//
#include <hip/hip_runtime.h>
#include <stdint.h>

#define S_LEN 2048
#define NH 16
#define DKH 64
#define NB 4
#define DM 1024
#define MROWS (NB * S_LEN)  // 8192

typedef __attribute__((ext_vector_type(4))) float f32x4;
typedef __attribute__((ext_vector_type(8))) short bf16x8;
typedef __attribute__((ext_vector_type(4))) unsigned int u32x4;

static __device__ __forceinline__ unsigned short f2bf(float x) {
    unsigned int u = __builtin_bit_cast(unsigned int, x);
    return (unsigned short)((u + 0x7FFFu + ((u >> 16) & 1u)) >> 16);
}
static __device__ __forceinline__ unsigned int pack2bf(float lo, float hi) {
    return (unsigned int)f2bf(lo) | ((unsigned int)f2bf(hi) << 16);
}

// CK-style addrspace cast via uintptr_t (apertures are 4GiB-aligned, low 32 bits = LDS offset)
static __device__ __forceinline__ void gld_lds16(const void* g, void* lds) {
    auto gp = (const __attribute__((address_space(1))) unsigned int*)(uintptr_t)(g);
    auto lp = (__attribute__((address_space(3))) unsigned int*)(uintptr_t)(lds);
    __builtin_amdgcn_global_load_lds(gp, lp, 16, 0, 0);
}

// ---------------- fp32 -> bf16 convert: 3-tensor (activations) and 4-tensor (weights) ----------------
__global__ __launch_bounds__(256) void cvt3_f32_bf16(
    const float* __restrict__ i0, const float* __restrict__ i1, const float* __restrict__ i2,
    unsigned short* __restrict__ o0, unsigned short* __restrict__ o1, unsigned short* __restrict__ o2,
    int nvec)
{
    const float* in = (blockIdx.z == 0) ? i0 : (blockIdx.z == 1) ? i1 : i2;
    unsigned short* out = (blockIdx.z == 0) ? o0 : (blockIdx.z == 1) ? o1 : o2;
    const int stride = gridDim.x * blockDim.x;
    for (int i = blockIdx.x * blockDim.x + threadIdx.x; i < nvec; i += stride) {
        float4 v = ((const float4*)in)[i];
        ushort4 r;
        r.x = f2bf(v.x); r.y = f2bf(v.y); r.z = f2bf(v.z); r.w = f2bf(v.w);
        ((ushort4*)out)[i] = r;
    }
}

__global__ __launch_bounds__(256) void cvt4_f32_bf16(
    const float* __restrict__ i0, const float* __restrict__ i1, const float* __restrict__ i2, const float* __restrict__ i3,
    unsigned short* __restrict__ o0, unsigned short* __restrict__ o1, unsigned short* __restrict__ o2, unsigned short* __restrict__ o3,
    int nvec)
{
    const float* in = (blockIdx.z == 0) ? i0 : (blockIdx.z == 1) ? i1 : (blockIdx.z == 2) ? i2 : i3;
    unsigned short* out = (blockIdx.z == 0) ? o0 : (blockIdx.z == 1) ? o1 : (blockIdx.z == 2) ? o2 : o3;
    const int stride = gridDim.x * blockDim.x;
    for (int i = blockIdx.x * blockDim.x + threadIdx.x; i < nvec; i += stride) {
        float4 v = ((const float4*)in)[i];
        ushort4 r;
        r.x = f2bf(v.x); r.y = f2bf(v.y); r.z = f2bf(v.z); r.w = f2bf(v.w);
        ((ushort4*)out)[i] = r;
    }
}

// ---------------- NT GEMM: C[m,n] = sum_k A[m,k]*B[n,k], M=8192 N=1024 K=1024 ----------------
// 128x128 tile, BK=64, 256 threads (4 waves, 2x2), 16x16x32 bf16 MFMA, global_load_lds staging.
// MODE 1: z=0,1 -> bf16 head-split [B,H,S,64] (z==0 scaled by qscale);
//         z=2   -> bf16 TRANSPOSED per-head V^T [B,H,64,S] (8B-vectorized stores).
// MODE 2: fp32 [M,N] row-major.
template <int MODE>
__global__ __launch_bounds__(256) void gemm_bt(
    const unsigned short* __restrict__ A0, const unsigned short* __restrict__ A1, const unsigned short* __restrict__ A2,
    const unsigned short* __restrict__ B0, const unsigned short* __restrict__ B1, const unsigned short* __restrict__ B2,
    void* __restrict__ C0, void* __restrict__ C1, void* __restrict__ C2, float qscale)
{
    __shared__ __align__(16) unsigned short As[128 * 64];
    __shared__ __align__(16) unsigned short Bs[128 * 64];
    const unsigned short* A = (blockIdx.z == 0) ? A0 : (blockIdx.z == 1) ? A1 : A2;
    const unsigned short* B = (blockIdx.z == 0) ? B0 : (blockIdx.z == 1) ? B1 : B2;
    void* C = (blockIdx.z == 0) ? C0 : (blockIdx.z == 1) ? C1 : C2;
    const float cscale = (MODE == 1 && blockIdx.z == 0) ? qscale : 1.0f;

    const int t = threadIdx.x;
    const int w = t >> 6, l = t & 63;
    const int wr = w >> 1, wc = w & 1;
    const int m0 = blockIdx.y * 128, n0 = blockIdx.x * 128;

    f32x4 acc[4][4] = {};

    const unsigned short* Ag = A + (size_t)(m0 + (t >> 3)) * 1024 + (t & 7) * 8;
    const unsigned short* Bg = B + (size_t)(n0 + (t >> 3)) * 1024 + (t & 7) * 8;
    unsigned short* AsW = &As[w * 512];
    unsigned short* BsW = &Bs[w * 512];

    for (int kt = 0; kt < 16; ++kt) {
        __syncthreads();
        const int kb = kt * 64;
#pragma unroll
        for (int i = 0; i < 4; ++i) {
            gld_lds16(Ag + (size_t)i * 32 * 1024 + kb, AsW + i * 2048);
            gld_lds16(Bg + (size_t)i * 32 * 1024 + kb, BsW + i * 2048);
        }
        __syncthreads();
#pragma unroll
        for (int kk = 0; kk < 2; ++kk) {
            const int koff = kk * 32 + (l >> 4) * 8;
            bf16x8 af[4], bfr[4];
#pragma unroll
            for (int m = 0; m < 4; ++m)
                af[m] = *(const bf16x8*)&As[(wr * 64 + m * 16 + (l & 15)) * 64 + koff];
#pragma unroll
            for (int n = 0; n < 4; ++n)
                bfr[n] = *(const bf16x8*)&Bs[(wc * 64 + n * 16 + (l & 15)) * 64 + koff];
#pragma unroll
            for (int m = 0; m < 4; ++m)
#pragma unroll
                for (int n = 0; n < 4; ++n)
                    acc[m][n] = __builtin_amdgcn_mfma_f32_16x16x32_bf16(af[m], bfr[n], acc[m][n], 0, 0, 0);
        }
    }

#pragma unroll
    for (int m = 0; m < 4; ++m) {
#pragma unroll
        for (int n = 0; n < 4; ++n) {
            const int rowb = m0 + wr * 64 + m * 16 + (l >> 4) * 4;       // +r = b*2048 + s
            const int col  = n0 + wc * 64 + n * 16 + (l & 15);           // = h*64 + dk
            if (MODE == 1 && blockIdx.z == 2) {
                // V^T store: [bh][dk][s], 4 consecutive s per lane -> 8B store
                const int bh = (rowb >> 11) * 16 + (col >> 6);
                const int dk = col & 63;
                const int s0 = rowb & 2047;
                const unsigned int w0 = pack2bf(acc[m][n][0], acc[m][n][1]);
                const unsigned int w1 = pack2bf(acc[m][n][2], acc[m][n][3]);
                *(uint2*)&((unsigned short*)C)[((size_t)bh * 64 + dk) * 2048 + s0] = make_uint2(w0, w1);
            } else {
#pragma unroll
                for (int r = 0; r < 4; ++r) {
                    const int row = rowb + r;
                    if (MODE == 1) {
                        ((unsigned short*)C)[(size_t)((row >> 11) * 16 + (col >> 6)) * (S_LEN * 64) +
                                             (size_t)(row & 2047) * 64 + (col & 63)] = f2bf(acc[m][n][r] * cscale);
                    } else {
                        ((float*)C)[(size_t)row * 1024 + col] = acc[m][n][r];
                    }
                }
            }
        }
    }
}

// ---------------- causal flash attention (swapped-QK^T, in-register softmax) ----------------
// Q/K [B*H, S, 64] bf16 (Q pre-scaled by 1/8), V^T [B*H, 64, S] bf16 -> Ao [B, S, 1024] bf16
// 512 threads = 8 waves, each wave owns 16 q-rows; KVBLK = 64.
// K and V^T double-buffered in LDS (4 x 8 KiB), staged via global_load_lds with pre-swizzled
// source (ch_phys = ch_log ^ (row&7)); ONE __syncthreads per tile, stage(kv+1) issued right
// after it (T3 minimum 2-phase: latency hides under compute of tile kv).
// After mfma(A=K, B=Q): sc[nb] = S^T[k = kv0+nb*16+4g+r][q = c], g=l>>4, c=l&15.
__global__ __launch_bounds__(512, 4) void attn_fwd(
    const unsigned short* __restrict__ Qh, const unsigned short* __restrict__ Kh,
    const unsigned short* __restrict__ Vth, unsigned short* __restrict__ Ao)
{
    __shared__ __align__(16) unsigned short Kts[2 * 4096];  // [buf][row 0..63][chunk 0..7][8]
    __shared__ __align__(16) unsigned short Vts[2 * 4096];  // [buf][dk 0..63][chunk 0..7][8]

    const int t = threadIdx.x, w = t >> 6, l = t & 63;
    const int g = l >> 4, c = l & 15;
    const int bid = blockIdx.x;
    const int qi = 15 - (bid >> 6);   // heavy-first: 32-tile blocks dispatch first
    const int bh = bid & 63;          // same-bh blocks land on same XCD (64 % 8 == 0)
    const int b = bh >> 4, h = bh & 15;
    const int q0 = qi * 128;

    const unsigned short* Qg  = Qh  + (size_t)bh * (S_LEN * 64);
    const unsigned short* Kg  = Kh  + (size_t)bh * (S_LEN * 64);
    const unsigned short* Vtg = Vth + (size_t)bh * (64 * S_LEN);

    // Q B-frags for this wave's 16 rows (held in regs for all tiles)
    const int qrow = q0 + w * 16 + c;
    const unsigned short* Qp = Qg + (size_t)qrow * 64 + g * 8;
    bf16x8 qf[2];
    qf[0] = *(const bf16x8*)(Qp);
    qf[1] = *(const bf16x8*)(Qp + 32);

    // staging: thread t handles 16B-unit L=t of each tile (512 units = 8KB).
    // K: row = t>>3 (64 rows x 64 dk), phys chunk = t&7, logical chunk = phys ^ (row&7)
    const int krow = t >> 3, kchp = t & 7;
    const unsigned short* Ksrc = Kg + (size_t)krow * 64 + ((kchp ^ (krow & 7)) << 3);
    // V: dk = t>>3 (64 dk x 64 kv), src row stride 2048
    const unsigned short* Vsrc = Vtg + (size_t)(t >> 3) * 2048 + ((kchp ^ ((t >> 3) & 7)) << 3);
    const int ldsW = w * 512;  // wave-uniform dest base (lane adds l*16B)

    float m_run = -1e30f, l_run = 0.0f;
    f32x4 oacc[4] = {};

    const int ntile = 2 * qi + 2;
    // prologue: stage tile 0 into buf 0
    gld_lds16(Ksrc, &Kts[ldsW]);
    gld_lds16(Vsrc, &Vts[ldsW]);

    for (int kv = 0; kv < ntile; ++kv) {
        const int kv0 = kv * 64;
        __syncthreads();  // stage(kv) drained & visible; all reads of buf[(kv+1)&1] done

        if (kv + 1 < ntile) {  // stage next tile (latency hides under this tile's compute)
            const int nb4 = ((kv + 1) & 1) * 4096;
            gld_lds16(Ksrc + (size_t)(kv0 + 64) * 64, &Kts[nb4 + ldsW]);
            gld_lds16(Vsrc + (kv0 + 64), &Vts[nb4 + ldsW]);
        }

        // skip fully-masked tiles for this wave (wave-uniform; barriers stay outside)
        if (kv0 > q0 + w * 16 + 15) continue;

        const unsigned short* Kb = &Kts[(kv & 1) * 4096];
        const unsigned short* Vb = &Vts[(kv & 1) * 4096];

        // --- QK^T (swapped): sc[nb] = S^T[k][q] ---
        f32x4 sc[4] = {};
#pragma unroll
        for (int kk = 0; kk < 2; ++kk) {
#pragma unroll
            for (int nb = 0; nb < 4; ++nb) {
                const int row = nb * 16 + c;
                const int chp = (kk * 4 + g) ^ (c & 7);
                const bf16x8 kfr = *(const bf16x8*)&Kb[row * 64 + chp * 8];
                sc[nb] = __builtin_amdgcn_mfma_f32_16x16x32_bf16(kfr, qf[kk], sc[nb], 0, 0, 0);
            }
        }

        // --- causal mask (only the last two tiles can touch the diagonal) ---
        if (kv >= ntile - 2) {
#pragma unroll
            for (int nb = 0; nb < 4; ++nb)
#pragma unroll
                for (int r = 0; r < 4; ++r)
                    if (kv0 + nb * 16 + 4 * g + r > qrow) sc[nb][r] = -1e30f;
        }

        // --- online softmax, in-register (q = c per lane), defer-max (T13, THR=8) ---
        float mx = -1e30f;
#pragma unroll
        for (int nb = 0; nb < 4; ++nb)
#pragma unroll
            for (int r = 0; r < 4; ++r) mx = fmaxf(mx, sc[nb][r]);
        mx = fmaxf(mx, __shfl_xor(mx, 16));
        mx = fmaxf(mx, __shfl_xor(mx, 32));

        if (!__all(mx - m_run <= 8.0f)) {
            const float mnew = fmaxf(m_run, mx);
            const float alpha = __expf(m_run - mnew);
            m_run = mnew;
            float af[4];
#pragma unroll
            for (int r = 0; r < 4; ++r) af[r] = __shfl(alpha, 4 * g + r);
#pragma unroll
            for (int db = 0; db < 4; ++db)
#pragma unroll
                for (int r = 0; r < 4; ++r) oacc[db][r] *= af[r];
            l_run *= alpha;
        }

        float s = 0.0f;
#pragma unroll
        for (int nb = 0; nb < 4; ++nb)
#pragma unroll
            for (int r = 0; r < 4; ++r) {
                const float p = __expf(sc[nb][r] - m_run);
                sc[nb][r] = p;
                s += p;
            }
        s += __shfl_xor(s, 16);
        s += __shfl_xor(s, 32);
        l_run += s;

        // --- pack P to bf16 pairs; redistribute into PV A-frags via shfl ---
        unsigned int pk[4][2];
#pragma unroll
        for (int nb = 0; nb < 4; ++nb) {
            pk[nb][0] = pack2bf(sc[nb][0], sc[nb][1]);
            pk[nb][1] = pack2bf(sc[nb][2], sc[nb][3]);
        }
        const int srcA = 32 * (g & 1) + c;
        const int srcB = srcA + 16;
        const bool hi = (g >= 2);   // selects k-block nb = 2*kk2 + 1
        unsigned int apw[2][4];
#pragma unroll
        for (int kk2 = 0; kk2 < 2; ++kk2) {
            const unsigned int a0 = __shfl(pk[2 * kk2][0], srcA), b0 = __shfl(pk[2 * kk2 + 1][0], srcA);
            const unsigned int a1 = __shfl(pk[2 * kk2][1], srcA), b1 = __shfl(pk[2 * kk2 + 1][1], srcA);
            const unsigned int a2 = __shfl(pk[2 * kk2][0], srcB), b2 = __shfl(pk[2 * kk2 + 1][0], srcB);
            const unsigned int a3 = __shfl(pk[2 * kk2][1], srcB), b3 = __shfl(pk[2 * kk2 + 1][1], srcB);
            apw[kk2][0] = hi ? b0 : a0;
            apw[kk2][1] = hi ? b1 : a1;
            apw[kk2][2] = hi ? b2 : a2;
            apw[kk2][3] = hi ? b3 : a3;
        }

        // --- PV: O += P * V  (A = apw regs, B = V^T rows from LDS, swizzled chunks) ---
#pragma unroll
        for (int kk2 = 0; kk2 < 2; ++kk2) {
            const bf16x8 ap = __builtin_bit_cast(bf16x8, *(const u32x4*)apw[kk2]);
#pragma unroll
            for (int db = 0; db < 4; ++db) {
                const int d = db * 16 + c;
                const int chp = (kk2 * 4 + g) ^ (d & 7);
                const bf16x8 bv = *(const bf16x8*)&Vb[d * 64 + chp * 8];
                oacc[db] = __builtin_amdgcn_mfma_f32_16x16x32_bf16(ap, bv, oacc[db], 0, 0, 0);
            }
        }
    }

    // --- epilogue: normalize, write [B, S, H*64] ---
    float li[4];
#pragma unroll
    for (int r = 0; r < 4; ++r) li[r] = __shfl(l_run, 4 * g + r);
#pragma unroll
    for (int db = 0; db < 4; ++db)
#pragma unroll
        for (int r = 0; r < 4; ++r) {
            const int sq = q0 + w * 16 + 4 * g + r;
            const int col = h * 64 + db * 16 + c;
            Ao[(size_t)b * (S_LEN * 1024) + (size_t)sq * 1024 + col] = f2bf(oacc[db][r] / li[r]);
        }
}

extern "C" void kernel_launch(void* const* d_in, const int* in_sizes, int n_in,
                              void* d_out, int out_size, void* d_ws, size_t ws_size,
                              hipStream_t stream) {
    (void)in_sizes; (void)n_in; (void)out_size; (void)ws_size;
    const float* q_in = (const float*)d_in[0];
    const float* k_in = (const float*)d_in[1];
    const float* v_in = (const float*)d_in[2];
    // d_in[3] = causal mask (tril) -> implemented analytically in attn_fwd
    const float* w_q = (const float*)d_in[4];
    const float* w_k = (const float*)d_in[5];
    const float* w_v = (const float*)d_in[6];
    const float* w_o = (const float*)d_in[7];

    const size_t NELEM = (size_t)MROWS * 1024;  // 8388608
    unsigned short* qb  = (unsigned short*)d_ws;
    unsigned short* kb  = qb + NELEM;
    unsigned short* vb  = kb + NELEM;
    unsigned short* wqb = vb + NELEM;
    unsigned short* wkb = wqb + 1024 * 1024;
    unsigned short* wvb = wkb + 1024 * 1024;
    unsigned short* wob = wvb + 1024 * 1024;
    unsigned short* Qhp = wob + 1024 * 1024;
    unsigned short* Khp = Qhp + NELEM;
    unsigned short* Vtp = Khp + NELEM;   // V^T [B*H, 64, S]
    unsigned short* Aop = qb;  // reuse: q/k/v bf16 dead after QKV GEMMs

    cvt3_f32_bf16<<<dim3(1024, 1, 3), 256, 0, stream>>>(q_in, k_in, v_in, qb, kb, vb, (int)(NELEM / 4));
    cvt4_f32_bf16<<<dim3(256, 1, 4), 256, 0, stream>>>(w_q, w_k, w_v, w_o, wqb, wkb, wvb, wob, 1024 * 1024 / 4);

    gemm_bt<1><<<dim3(8, 64, 3), 256, 0, stream>>>(qb, kb, vb, wqb, wkb, wvb, Qhp, Khp, Vtp, 0.125f);
    attn_fwd<<<dim3(1024), 512, 0, stream>>>(Qhp, Khp, Vtp, Aop);
    gemm_bt<2><<<dim3(8, 64, 1), 256, 0, stream>>>(Aop, nullptr, nullptr, wob, nullptr, nullptr,
                                                   d_out, nullptr, nullptr, 1.0f);
}

// Round 7
// 326.052 us; speedup vs baseline: 2.0592x; 1.0523x over previous
//
#include <hip/hip_runtime.h>
#include <stdint.h>

#define S_LEN 2048
#define NH 16
#define DKH 64
#define NB 4
#define DM 1024
#define MROWS (NB * S_LEN)  // 8192

typedef __attribute__((ext_vector_type(4))) float f32x4;
typedef __attribute__((ext_vector_type(8))) short bf16x8;
typedef __attribute__((ext_vector_type(4))) unsigned int u32x4;

static __device__ __forceinline__ unsigned short f2bf(float x) {
    unsigned int u = __builtin_bit_cast(unsigned int, x);
    return (unsigned short)((u + 0x7FFFu + ((u >> 16) & 1u)) >> 16);
}
static __device__ __forceinline__ unsigned int pack2bf(float lo, float hi) {
    return (unsigned int)f2bf(lo) | ((unsigned int)f2bf(hi) << 16);
}

// CK-style addrspace cast via uintptr_t (apertures are 4GiB-aligned, low 32 bits = LDS offset)
static __device__ __forceinline__ void gld_lds16(const void* g, void* lds) {
    auto gp = (const __attribute__((address_space(1))) unsigned int*)(uintptr_t)(g);
    auto lp = (__attribute__((address_space(3))) unsigned int*)(uintptr_t)(lds);
    __builtin_amdgcn_global_load_lds(gp, lp, 16, 0, 0);
}

// ---------------- fp32 -> bf16 convert: 3-tensor (activations) and 4-tensor (weights) ----------------
__global__ __launch_bounds__(256) void cvt3_f32_bf16(
    const float* __restrict__ i0, const float* __restrict__ i1, const float* __restrict__ i2,
    unsigned short* __restrict__ o0, unsigned short* __restrict__ o1, unsigned short* __restrict__ o2,
    int nvec)
{
    const float* in = (blockIdx.z == 0) ? i0 : (blockIdx.z == 1) ? i1 : i2;
    unsigned short* out = (blockIdx.z == 0) ? o0 : (blockIdx.z == 1) ? o1 : o2;
    const int stride = gridDim.x * blockDim.x;
    for (int i = blockIdx.x * blockDim.x + threadIdx.x; i < nvec; i += stride) {
        float4 v = ((const float4*)in)[i];
        ushort4 r;
        r.x = f2bf(v.x); r.y = f2bf(v.y); r.z = f2bf(v.z); r.w = f2bf(v.w);
        ((ushort4*)out)[i] = r;
    }
}

__global__ __launch_bounds__(256) void cvt4_f32_bf16(
    const float* __restrict__ i0, const float* __restrict__ i1, const float* __restrict__ i2, const float* __restrict__ i3,
    unsigned short* __restrict__ o0, unsigned short* __restrict__ o1, unsigned short* __restrict__ o2, unsigned short* __restrict__ o3,
    int nvec)
{
    const float* in = (blockIdx.z == 0) ? i0 : (blockIdx.z == 1) ? i1 : (blockIdx.z == 2) ? i2 : i3;
    unsigned short* out = (blockIdx.z == 0) ? o0 : (blockIdx.z == 1) ? o1 : (blockIdx.z == 2) ? o2 : o3;
    const int stride = gridDim.x * blockDim.x;
    for (int i = blockIdx.x * blockDim.x + threadIdx.x; i < nvec; i += stride) {
        float4 v = ((const float4*)in)[i];
        ushort4 r;
        r.x = f2bf(v.x); r.y = f2bf(v.y); r.z = f2bf(v.z); r.w = f2bf(v.w);
        ((ushort4*)out)[i] = r;
    }
}

// ---------------- NT GEMM: C[m,n] = sum_k A[m,k]*B[n,k], M=8192 N=1024 K=1024 ----------------
// 128x128 tile, BK=64, 256 threads (4 waves, 2x2), 16x16x32 bf16 MFMA, global_load_lds staging.
// T1: bijective XCD swizzle so all 8 n-blocks of an A-panel run consecutively on ONE XCD.
// T2: LDS chunk swizzle (phys = log ^ (row&7)) via pre-swizzled global source; linear LDS dest.
// MODE 1: z=0,1 -> bf16 head-split [B,H,S,64] (z==0 scaled by qscale);
//         z=2   -> bf16 TRANSPOSED per-head V^T [B,H,64,S] (8B-vectorized stores).
// MODE 2: fp32 [M,N] row-major.
template <int MODE>
__global__ __launch_bounds__(256) void gemm_bt(
    const unsigned short* __restrict__ A0, const unsigned short* __restrict__ A1, const unsigned short* __restrict__ A2,
    const unsigned short* __restrict__ B0, const unsigned short* __restrict__ B1, const unsigned short* __restrict__ B2,
    void* __restrict__ C0, void* __restrict__ C1, void* __restrict__ C2, float qscale)
{
    __shared__ __align__(16) unsigned short As[128 * 64];
    __shared__ __align__(16) unsigned short Bs[128 * 64];

    // T1 bijective XCD swizzle (nwg % 8 == 0 always here)
    const int nwg = gridDim.x * gridDim.y * gridDim.z;
    const int bid = blockIdx.x + gridDim.x * (blockIdx.y + gridDim.y * blockIdx.z);
    const int swz = (bid & 7) * (nwg >> 3) + (bid >> 3);
    const int bx = swz & 7;              // n-block
    const int by = (swz >> 3) & 63;      // m-panel
    const int bz = swz >> 9;             // tensor index (0 for MODE 2: swz < 512)

    const unsigned short* A = (bz == 0) ? A0 : (bz == 1) ? A1 : A2;
    const unsigned short* B = (bz == 0) ? B0 : (bz == 1) ? B1 : B2;
    void* C = (bz == 0) ? C0 : (bz == 1) ? C1 : C2;
    const float cscale = (MODE == 1 && bz == 0) ? qscale : 1.0f;

    const int t = threadIdx.x;
    const int w = t >> 6, l = t & 63;
    const int wr = w >> 1, wc = w & 1;
    const int m0 = by * 128, n0 = bx * 128;

    f32x4 acc[4][4] = {};

    // staging: thread t covers row (t>>3)+32*i, phys 16B chunk (t&7); LDS dest linear in t.
    // T2: phys chunk holds logical chunk (t&7)^(row&7)  ->  pre-swizzle the GLOBAL source col.
    const int srow = t >> 3, schp = t & 7;
    const int scol = ((schp ^ (srow & 7)) << 3);
    const unsigned short* Ag = A + (size_t)(m0 + srow) * 1024 + scol;
    const unsigned short* Bg = B + (size_t)(n0 + srow) * 1024 + scol;
    unsigned short* AsW = &As[w * 512];
    unsigned short* BsW = &Bs[w * 512];

    for (int kt = 0; kt < 16; ++kt) {
        __syncthreads();
        const int kb = kt * 64;
#pragma unroll
        for (int i = 0; i < 4; ++i) {
            gld_lds16(Ag + (size_t)i * 32 * 1024 + kb, AsW + i * 2048);
            gld_lds16(Bg + (size_t)i * 32 * 1024 + kb, BsW + i * 2048);
        }
        __syncthreads();
#pragma unroll
        for (int kk = 0; kk < 2; ++kk) {
            // fragment rows have row&7 == l&7 -> phys chunk = (kk*4 + (l>>4)) ^ (l&7)
            const int koff = (((kk * 4 + (l >> 4)) ^ (l & 7)) << 3);
            bf16x8 af[4], bfr[4];
#pragma unroll
            for (int m = 0; m < 4; ++m)
                af[m] = *(const bf16x8*)&As[(wr * 64 + m * 16 + (l & 15)) * 64 + koff];
#pragma unroll
            for (int n = 0; n < 4; ++n)
                bfr[n] = *(const bf16x8*)&Bs[(wc * 64 + n * 16 + (l & 15)) * 64 + koff];
#pragma unroll
            for (int m = 0; m < 4; ++m)
#pragma unroll
                for (int n = 0; n < 4; ++n)
                    acc[m][n] = __builtin_amdgcn_mfma_f32_16x16x32_bf16(af[m], bfr[n], acc[m][n], 0, 0, 0);
        }
    }

#pragma unroll
    for (int m = 0; m < 4; ++m) {
#pragma unroll
        for (int n = 0; n < 4; ++n) {
            const int rowb = m0 + wr * 64 + m * 16 + (l >> 4) * 4;       // +r = b*2048 + s
            const int col  = n0 + wc * 64 + n * 16 + (l & 15);           // = h*64 + dk
            if (MODE == 1 && bz == 2) {
                // V^T store: [bh][dk][s], 4 consecutive s per lane -> 8B store
                const int bh = (rowb >> 11) * 16 + (col >> 6);
                const int dk = col & 63;
                const int s0 = rowb & 2047;
                const unsigned int w0 = pack2bf(acc[m][n][0], acc[m][n][1]);
                const unsigned int w1 = pack2bf(acc[m][n][2], acc[m][n][3]);
                *(uint2*)&((unsigned short*)C)[((size_t)bh * 64 + dk) * 2048 + s0] = make_uint2(w0, w1);
            } else {
#pragma unroll
                for (int r = 0; r < 4; ++r) {
                    const int row = rowb + r;
                    if (MODE == 1) {
                        ((unsigned short*)C)[(size_t)((row >> 11) * 16 + (col >> 6)) * (S_LEN * 64) +
                                             (size_t)(row & 2047) * 64 + (col & 63)] = f2bf(acc[m][n][r] * cscale);
                    } else {
                        ((float*)C)[(size_t)row * 1024 + col] = acc[m][n][r];
                    }
                }
            }
        }
    }
}

// ---------------- causal flash attention (swapped-QK^T, in-register softmax) ----------------
// Q/K [B*H, S, 64] bf16 (Q pre-scaled by 1/8), V^T [B*H, 64, S] bf16 -> Ao [B, S, 1024] bf16
// 512 threads = 8 waves, each wave owns 16 q-rows; KVBLK = 64.
// K and V^T double-buffered in LDS (4 x 8 KiB), staged via global_load_lds with pre-swizzled
// source (ch_phys = ch_log ^ (row&7)); ONE __syncthreads per tile, stage(kv+1) issued right
// after it (T3 minimum 2-phase: latency hides under compute of tile kv).
// After mfma(A=K, B=Q): sc[nb] = S^T[k = kv0+nb*16+4g+r][q = c], g=l>>4, c=l&15.
__global__ __launch_bounds__(512, 4) void attn_fwd(
    const unsigned short* __restrict__ Qh, const unsigned short* __restrict__ Kh,
    const unsigned short* __restrict__ Vth, unsigned short* __restrict__ Ao)
{
    __shared__ __align__(16) unsigned short Kts[2 * 4096];  // [buf][row 0..63][chunk 0..7][8]
    __shared__ __align__(16) unsigned short Vts[2 * 4096];  // [buf][dk 0..63][chunk 0..7][8]

    const int t = threadIdx.x, w = t >> 6, l = t & 63;
    const int g = l >> 4, c = l & 15;
    const int bid = blockIdx.x;
    const int qi = 15 - (bid >> 6);   // heavy-first: 32-tile blocks dispatch first
    const int bh = bid & 63;          // same-bh blocks land on same XCD (64 % 8 == 0)
    const int b = bh >> 4, h = bh & 15;
    const int q0 = qi * 128;

    const unsigned short* Qg  = Qh  + (size_t)bh * (S_LEN * 64);
    const unsigned short* Kg  = Kh  + (size_t)bh * (S_LEN * 64);
    const unsigned short* Vtg = Vth + (size_t)bh * (64 * S_LEN);

    // Q B-frags for this wave's 16 rows (held in regs for all tiles)
    const int qrow = q0 + w * 16 + c;
    const unsigned short* Qp = Qg + (size_t)qrow * 64 + g * 8;
    bf16x8 qf[2];
    qf[0] = *(const bf16x8*)(Qp);
    qf[1] = *(const bf16x8*)(Qp + 32);

    // staging: thread t handles 16B-unit L=t of each tile (512 units = 8KB).
    // K: row = t>>3 (64 rows x 64 dk), phys chunk = t&7, logical chunk = phys ^ (row&7)
    const int krow = t >> 3, kchp = t & 7;
    const unsigned short* Ksrc = Kg + (size_t)krow * 64 + ((kchp ^ (krow & 7)) << 3);
    // V: dk = t>>3 (64 dk x 64 kv), src row stride 2048
    const unsigned short* Vsrc = Vtg + (size_t)(t >> 3) * 2048 + ((kchp ^ ((t >> 3) & 7)) << 3);
    const int ldsW = w * 512;  // wave-uniform dest base (lane adds l*16B)

    float m_run = -1e30f, l_run = 0.0f;
    f32x4 oacc[4] = {};

    const int ntile = 2 * qi + 2;
    // prologue: stage tile 0 into buf 0
    gld_lds16(Ksrc, &Kts[ldsW]);
    gld_lds16(Vsrc, &Vts[ldsW]);

    for (int kv = 0; kv < ntile; ++kv) {
        const int kv0 = kv * 64;
        __syncthreads();  // stage(kv) drained & visible; all reads of buf[(kv+1)&1] done

        if (kv + 1 < ntile) {  // stage next tile (latency hides under this tile's compute)
            const int nb4 = ((kv + 1) & 1) * 4096;
            gld_lds16(Ksrc + (size_t)(kv0 + 64) * 64, &Kts[nb4 + ldsW]);
            gld_lds16(Vsrc + (kv0 + 64), &Vts[nb4 + ldsW]);
        }

        // skip fully-masked tiles for this wave (wave-uniform; barriers stay outside)
        if (kv0 > q0 + w * 16 + 15) continue;

        const unsigned short* Kb = &Kts[(kv & 1) * 4096];
        const unsigned short* Vb = &Vts[(kv & 1) * 4096];

        // --- QK^T (swapped): sc[nb] = S^T[k][q] ---
        f32x4 sc[4] = {};
#pragma unroll
        for (int kk = 0; kk < 2; ++kk) {
#pragma unroll
            for (int nb = 0; nb < 4; ++nb) {
                const int row = nb * 16 + c;
                const int chp = (kk * 4 + g) ^ (c & 7);
                const bf16x8 kfr = *(const bf16x8*)&Kb[row * 64 + chp * 8];
                sc[nb] = __builtin_amdgcn_mfma_f32_16x16x32_bf16(kfr, qf[kk], sc[nb], 0, 0, 0);
            }
        }

        // --- causal mask (only the last two tiles can touch the diagonal) ---
        if (kv >= ntile - 2) {
#pragma unroll
            for (int nb = 0; nb < 4; ++nb)
#pragma unroll
                for (int r = 0; r < 4; ++r)
                    if (kv0 + nb * 16 + 4 * g + r > qrow) sc[nb][r] = -1e30f;
        }

        // --- online softmax, in-register (q = c per lane), defer-max (T13, THR=8) ---
        float mx = -1e30f;
#pragma unroll
        for (int nb = 0; nb < 4; ++nb)
#pragma unroll
            for (int r = 0; r < 4; ++r) mx = fmaxf(mx, sc[nb][r]);
        mx = fmaxf(mx, __shfl_xor(mx, 16));
        mx = fmaxf(mx, __shfl_xor(mx, 32));

        if (!__all(mx - m_run <= 8.0f)) {
            const float mnew = fmaxf(m_run, mx);
            const float alpha = __expf(m_run - mnew);
            m_run = mnew;
            float af[4];
#pragma unroll
            for (int r = 0; r < 4; ++r) af[r] = __shfl(alpha, 4 * g + r);
#pragma unroll
            for (int db = 0; db < 4; ++db)
#pragma unroll
                for (int r = 0; r < 4; ++r) oacc[db][r] *= af[r];
            l_run *= alpha;
        }

        float s = 0.0f;
#pragma unroll
        for (int nb = 0; nb < 4; ++nb)
#pragma unroll
            for (int r = 0; r < 4; ++r) {
                const float p = __expf(sc[nb][r] - m_run);
                sc[nb][r] = p;
                s += p;
            }
        s += __shfl_xor(s, 16);
        s += __shfl_xor(s, 32);
        l_run += s;

        // --- pack P to bf16 pairs; redistribute into PV A-frags via shfl ---
        unsigned int pk[4][2];
#pragma unroll
        for (int nb = 0; nb < 4; ++nb) {
            pk[nb][0] = pack2bf(sc[nb][0], sc[nb][1]);
            pk[nb][1] = pack2bf(sc[nb][2], sc[nb][3]);
        }
        const int srcA = 32 * (g & 1) + c;
        const int srcB = srcA + 16;
        const bool hi = (g >= 2);   // selects k-block nb = 2*kk2 + 1
        unsigned int apw[2][4];
#pragma unroll
        for (int kk2 = 0; kk2 < 2; ++kk2) {
            const unsigned int a0 = __shfl(pk[2 * kk2][0], srcA), b0 = __shfl(pk[2 * kk2 + 1][0], srcA);
            const unsigned int a1 = __shfl(pk[2 * kk2][1], srcA), b1 = __shfl(pk[2 * kk2 + 1][1], srcA);
            const unsigned int a2 = __shfl(pk[2 * kk2][0], srcB), b2 = __shfl(pk[2 * kk2 + 1][0], srcB);
            const unsigned int a3 = __shfl(pk[2 * kk2][1], srcB), b3 = __shfl(pk[2 * kk2 + 1][1], srcB);
            apw[kk2][0] = hi ? b0 : a0;
            apw[kk2][1] = hi ? b1 : a1;
            apw[kk2][2] = hi ? b2 : a2;
            apw[kk2][3] = hi ? b3 : a3;
        }

        // --- PV: O += P * V  (A = apw regs, B = V^T rows from LDS, swizzled chunks) ---
#pragma unroll
        for (int kk2 = 0; kk2 < 2; ++kk2) {
            const bf16x8 ap = __builtin_bit_cast(bf16x8, *(const u32x4*)apw[kk2]);
#pragma unroll
            for (int db = 0; db < 4; ++db) {
                const int d = db * 16 + c;
                const int chp = (kk2 * 4 + g) ^ (d & 7);
                const bf16x8 bv = *(const bf16x8*)&Vb[d * 64 + chp * 8];
                oacc[db] = __builtin_amdgcn_mfma_f32_16x16x32_bf16(ap, bv, oacc[db], 0, 0, 0);
            }
        }
    }

    // --- epilogue: normalize, write [B, S, H*64] ---
    float li[4];
#pragma unroll
    for (int r = 0; r < 4; ++r) li[r] = __shfl(l_run, 4 * g + r);
#pragma unroll
    for (int db = 0; db < 4; ++db)
#pragma unroll
        for (int r = 0; r < 4; ++r) {
            const int sq = q0 + w * 16 + 4 * g + r;
            const int col = h * 64 + db * 16 + c;
            Ao[(size_t)b * (S_LEN * 1024) + (size_t)sq * 1024 + col] = f2bf(oacc[db][r] / li[r]);
        }
}

extern "C" void kernel_launch(void* const* d_in, const int* in_sizes, int n_in,
                              void* d_out, int out_size, void* d_ws, size_t ws_size,
                              hipStream_t stream) {
    (void)in_sizes; (void)n_in; (void)out_size; (void)ws_size;
    const float* q_in = (const float*)d_in[0];
    const float* k_in = (const float*)d_in[1];
    const float* v_in = (const float*)d_in[2];
    // d_in[3] = causal mask (tril) -> implemented analytically in attn_fwd
    const float* w_q = (const float*)d_in[4];
    const float* w_k = (const float*)d_in[5];
    const float* w_v = (const float*)d_in[6];
    const float* w_o = (const float*)d_in[7];

    const size_t NELEM = (size_t)MROWS * 1024;  // 8388608
    unsigned short* qb  = (unsigned short*)d_ws;
    unsigned short* kb  = qb + NELEM;
    unsigned short* vb  = kb + NELEM;
    unsigned short* wqb = vb + NELEM;
    unsigned short* wkb = wqb + 1024 * 1024;
    unsigned short* wvb = wkb + 1024 * 1024;
    unsigned short* wob = wvb + 1024 * 1024;
    unsigned short* Qhp = wob + 1024 * 1024;
    unsigned short* Khp = Qhp + NELEM;
    unsigned short* Vtp = Khp + NELEM;   // V^T [B*H, 64, S]
    unsigned short* Aop = qb;  // reuse: q/k/v bf16 dead after QKV GEMMs

    cvt3_f32_bf16<<<dim3(1024, 1, 3), 256, 0, stream>>>(q_in, k_in, v_in, qb, kb, vb, (int)(NELEM / 4));
    cvt4_f32_bf16<<<dim3(256, 1, 4), 256, 0, stream>>>(w_q, w_k, w_v, w_o, wqb, wkb, wvb, wob, 1024 * 1024 / 4);

    gemm_bt<1><<<dim3(8, 64, 3), 256, 0, stream>>>(qb, kb, vb, wqb, wkb, wvb, Qhp, Khp, Vtp, 0.125f);
    attn_fwd<<<dim3(1024), 512, 0, stream>>>(Qhp, Khp, Vtp, Aop);
    gemm_bt<2><<<dim3(8, 64, 1), 256, 0, stream>>>(Aop, nullptr, nullptr, wob, nullptr, nullptr,
                                                   d_out, nullptr, nullptr, 1.0f);
}